// Round 14
// baseline (189.554 us; speedup 1.0000x reference)
//
#include <hip/hip_runtime.h>
#include <hip/hip_bf16.h>
#include <math.h>

// PairwiseCosineSimilarity: C[n][m] = <x1[n],x2[m]> / (max(||x1||,eps)*max(||x2||,eps))
// Round 14: r13 winning structure (128x128 tile, single-buffered 32 KB LDS,
// 2-sync loop, 4 blocks/CU co-residency, supertile L2 mapping) with the MFMA
// shape switched 16x16x32 -> 32x32x16:
//   - same FLOPs in 16 MFMA (~128 cyc) instead of 32 (~155 cyc) per K-tile/wave
//     (m119: 2495 vs 2176 TF ubench), identical LDS traffic (16x ds_read_b128).
//   - per wave 64x64 = 2x2 frags of 32x32; acc f32x16 x4 = 64 VGPR (same).
//   - layouts: C/D col=lane&31, row=(reg&3)+8*(reg>>2)+4*(lane>>5)  [m74/m101]
//              A/B  row/col=lane&31, k=(lane>>5)*8+j
// Everything else identical to r13 (verified passing, 166.6 us).

typedef __bf16 bf16x8 __attribute__((ext_vector_type(8)));
typedef float  f32x16 __attribute__((ext_vector_type(16)));

#define LDSP(x) ((__attribute__((address_space(3))) void*)(x))
#define GLBP(x) ((const __attribute__((address_space(1))) void*)(x))

#define BM 128
#define BN 128
#define BK 64
#define EPS_CS 1e-8f

// ------------- normalize: one block per row of x1 or x2, D == 1024 -------------

__global__ __launch_bounds__(256) void nrm_bf16_1024_2(const float* __restrict__ in1,
                                                       const float* __restrict__ in2,
                                                       __bf16* __restrict__ out1,
                                                       __bf16* __restrict__ out2,
                                                       int NR) {
    const int r = blockIdx.x;
    const float* in = (r < NR) ? in1 : in2;
    __bf16* out = (r < NR) ? out1 : out2;
    const int row = (r < NR) ? r : r - NR;
    const int t = threadIdx.x;
    const float4 v = reinterpret_cast<const float4*>(in + (size_t)row * 1024)[t];
    float ss = v.x * v.x + v.y * v.y + v.z * v.z + v.w * v.w;
#pragma unroll
    for (int off = 32; off > 0; off >>= 1) ss += __shfl_down(ss, off, 64);
    __shared__ float red[4];
    const int lane = t & 63, wid = t >> 6;
    if (lane == 0) red[wid] = ss;
    __syncthreads();
    const float tot = red[0] + red[1] + red[2] + red[3];
    const float rn = 1.0f / fmaxf(sqrtf(tot), EPS_CS);
    ushort4 pk;
    pk.x = __builtin_bit_cast(unsigned short, (__bf16)(v.x * rn));
    pk.y = __builtin_bit_cast(unsigned short, (__bf16)(v.y * rn));
    pk.z = __builtin_bit_cast(unsigned short, (__bf16)(v.z * rn));
    pk.w = __builtin_bit_cast(unsigned short, (__bf16)(v.w * rn));
    reinterpret_cast<ushort4*>(out + (size_t)row * 1024)[t] = pk;
}

// ---------------- 128x128 m97-structure MFMA GEMM (32x32x16):  C = A * B^T ----------------
// A[NR][D], B[NC][D] bf16 row-major; C[NR][NC] f32. NR,NC % 128 == 0, D % 64 == 0.
// Grid = (NR/128)*(NC/128), block = 256 (4 waves, 2x2). Per wave: 64x64 output,
// acc[2][2] f32x16 = 64 VGPR. LDS: A[128x64] + B[128x64] bf16 = 32 KB, single-buf.
// __launch_bounds__(256,4): 4 waves/EU -> VGPR<=128 -> 4 blocks/CU co-resident.

__global__ __launch_bounds__(256, 4) void gemm_nt_bf16_128(const __bf16* __restrict__ A,
                                                           const __bf16* __restrict__ B,
                                                           float* __restrict__ C,
                                                           int NC, int D) {
    __shared__ alignas(16) __bf16 As[BM * BK];   // 16 KB
    __shared__ alignas(16) __bf16 Bs[BN * BK];   // 16 KB

    const int t    = threadIdx.x;
    const int lane = t & 63;
    const int wid  = t >> 6;            // 0..3
    const int wr   = wid >> 1;          // wave row 0..1 (64-row strips)
    const int wc   = wid & 1;           // wave col 0..1 (64-col strips)
    const int r31  = lane & 31;         // fragment row/col within 32
    const int fh   = lane >> 5;         // k-half (0/1): k = fh*8 + j within 16
    const int xk   = r31 & 7;           // read XOR key == (row & 7)

    // ---- block -> tile mapping: 2-D supertile (16 rows x 8 cols per XCD) ----
    const int nwg = gridDim.x;
    const int ntn = NC / BN;
    const int ntm = nwg / ntn;
    int tr, tc;
    if (ntn == 64 && (ntm & 15) == 0) {
        const int xcd = blockIdx.x & 7;
        const int i   = blockIdx.x >> 3;    // 0 .. nwg/8-1
        const int gen = i >> 7;             // supertile generation (16 tile-rows each)
        const int w   = i & 127;            // position within 16x8 supertile
        tr = gen * 16 + (w & 15);
        tc = xcd * 8 + (w >> 4);
    } else if ((nwg & 7) == 0) {
        const int swz = (blockIdx.x & 7) * (nwg >> 3) + (blockIdx.x >> 3);
        tr = swz / ntn; tc = swz % ntn;
    } else {
        tr = blockIdx.x / ntn; tc = blockIdx.x % ntn;
    }
    const int brow = tr * BM;
    const int bcol = tc * BN;

    // staging: thread t covers LDS elements [s*8, s*8+8) of slab s = i*256+t.
    // row = i*32 + (t>>3), lds k-group = t&7; global k-group pre-swizzled:
    // (t&7) ^ (row&7)  (inverse of the read XOR).
    const int srow = t >> 3;                         // 0..31
    const int sg8  = ((t & 7) ^ (srow & 7)) << 3;
    const __bf16* aSrc = A + (size_t)(brow + srow) * D + sg8;
    const __bf16* bSrc = B + (size_t)(bcol + srow) * D + sg8;

    f32x16 acc[2][2];
#pragma unroll
    for (int m = 0; m < 2; ++m)
#pragma unroll
        for (int n = 0; n < 2; ++n)
#pragma unroll
            for (int r = 0; r < 16; ++r)
                acc[m][n][r] = 0.f;

    const int NT = D / BK;
    for (int kt = 0; kt < NT; ++kt) {
        const int k0 = kt * BK;
        // ---- stage A,B tiles (128x64 bf16 each) via global_load_lds x16B ----
#pragma unroll
        for (int i = 0; i < 4; ++i)
            __builtin_amdgcn_global_load_lds(
                GLBP(aSrc + (size_t)(i * 32) * D + k0),
                LDSP(&As[(i * 256 + t) * 8]), 16, 0, 0);
#pragma unroll
        for (int i = 0; i < 4; ++i)
            __builtin_amdgcn_global_load_lds(
                GLBP(bSrc + (size_t)(i * 32) * D + k0),
                LDSP(&Bs[(i * 256 + t) * 8]), 16, 0, 0);
        __syncthreads();   // compiler drains vmcnt before s_barrier

        // ---- compute: 4 k-steps of 16, 4 MFMA (32x32x16) each ----
#pragma unroll
        for (int ks = 0; ks < 4; ++ks) {
            const int g = (ks * 2 + fh) ^ xk;   // physical 16B-group of this k-step
            bf16x8 af[2], bf[2];
#pragma unroll
            for (int m = 0; m < 2; ++m)
                af[m] = *reinterpret_cast<const bf16x8*>(&As[(wr * 64 + m * 32 + r31) * BK + g * 8]);
#pragma unroll
            for (int n = 0; n < 2; ++n)
                bf[n] = *reinterpret_cast<const bf16x8*>(&Bs[(wc * 64 + n * 32 + r31) * BK + g * 8]);
#pragma unroll
            for (int m = 0; m < 2; ++m)
#pragma unroll
                for (int n = 0; n < 2; ++n)
                    acc[m][n] = __builtin_amdgcn_mfma_f32_32x32x16_bf16(af[m], bf[n], acc[m][n], 0, 0, 0);
        }
        __syncthreads();   // protect LDS from next iteration's staging
    }

    // ---- epilogue: col = lane&31, row = (reg&3) + 8*(reg>>2) + 4*(lane>>5) ----
    const int crow0 = brow + wr * 64;
    const int ccol0 = bcol + wc * 64;
#pragma unroll
    for (int m = 0; m < 2; ++m) {
#pragma unroll
        for (int rg = 0; rg < 4; ++rg) {         // reg>>2
#pragma unroll
            for (int rl = 0; rl < 4; ++rl) {     // reg&3
                const int row = crow0 + m * 32 + rl + 8 * rg + 4 * fh;
                const size_t rowoff = (size_t)row * NC;
#pragma unroll
                for (int n = 0; n < 2; ++n)
                    C[rowoff + ccol0 + n * 32 + r31] = acc[m][n][rg * 4 + rl];
            }
        }
    }
}

// ---------------- fallback path (odd shapes / tiny ws) ----------------

__global__ __launch_bounds__(256) void rnorm_rows(const float* __restrict__ in,
                                                  float* __restrict__ rn, int D) {
    const int row = blockIdx.x;
    float ss = 0.f;
    for (int c = threadIdx.x; c < D; c += 256) {
        const float v = in[(size_t)row * D + c];
        ss += v * v;
    }
#pragma unroll
    for (int off = 32; off > 0; off >>= 1) ss += __shfl_down(ss, off, 64);
    __shared__ float red[4];
    if ((threadIdx.x & 63) == 0) red[threadIdx.x >> 6] = ss;
    __syncthreads();
    if (threadIdx.x == 0) {
        const float tot = red[0] + red[1] + red[2] + red[3];
        rn[row] = 1.0f / fmaxf(sqrtf(tot), EPS_CS);
    }
}

__global__ __launch_bounds__(256) void gemm_f32_fallback(const float* __restrict__ x1,
                                                         const float* __restrict__ x2,
                                                         const float* __restrict__ rn1,
                                                         const float* __restrict__ rn2,
                                                         float* __restrict__ C,
                                                         int NR, int NC, int D) {
    __shared__ float a[16][17], b[16][17];
    const int tx = threadIdx.x & 15, ty = threadIdx.x >> 4;
    const int row = blockIdx.y * 16 + ty;
    const int colb = blockIdx.x * 16;
    float acc = 0.f;
    for (int k0 = 0; k0 < D; k0 += 16) {
        a[ty][tx] = (row < NR && k0 + tx < D) ? x1[(size_t)row * D + k0 + tx] : 0.f;
        b[ty][tx] = (colb + ty < NC && k0 + tx < D) ? x2[(size_t)(colb + ty) * D + k0 + tx] : 0.f;
        __syncthreads();
#pragma unroll
        for (int k = 0; k < 16; ++k) acc += a[ty][k] * b[tx][k];
        __syncthreads();
    }
    if (row < NR && colb + tx < NC)
        C[(size_t)row * NC + colb + tx] = acc * rn1[row] * rn2[colb + tx];
}

// ---------------- launch ----------------

extern "C" void kernel_launch(void* const* d_in, const int* in_sizes, int n_in,
                              void* d_out, int out_size, void* d_ws, size_t ws_size,
                              hipStream_t stream) {
    const float* x1 = (const float*)d_in[0];
    const float* x2 = (const float*)d_in[1];
    float* C = (float*)d_out;

    const int D  = 1024;
    const int NR = in_sizes[0] / D;
    const int NC = in_sizes[1] / D;

    const size_t need = ((size_t)NR + (size_t)NC) * (size_t)D * sizeof(__bf16);
    const bool fast = (in_sizes[0] % D == 0) && (in_sizes[1] % D == 0) &&
                      (NR % BM == 0) && (NC % BN == 0) && (D % BK == 0) &&
                      (ws_size >= need);

    if (fast) {
        __bf16* An = (__bf16*)d_ws;
        __bf16* Bn = An + (size_t)NR * D;
        nrm_bf16_1024_2<<<NR + NC, 256, 0, stream>>>(x1, x2, An, Bn, NR);
        const int grid = (NR / BM) * (NC / BN);
        gemm_nt_bf16_128<<<grid, 256, 0, stream>>>(An, Bn, C, NC, D);
    } else {
        float* rn1 = (float*)d_ws;
        float* rn2 = rn1 + NR;
        rnorm_rows<<<NR, 256, 0, stream>>>(x1, rn1, D);
        rnorm_rows<<<NC, 256, 0, stream>>>(x2, rn2, D);
        dim3 g((NC + 15) / 16, (NR + 15) / 16);
        gemm_f32_fallback<<<g, 256, 0, stream>>>(x1, x2, rn1, rn2, C, NR, NC, D);
    }
}

// Round 15
// 166.779 us; speedup vs baseline: 1.1366x; 1.1366x over previous
//
#include <hip/hip_runtime.h>
#include <hip/hip_bf16.h>
#include <math.h>

// PairwiseCosineSimilarity: C[n][m] = <x1[n],x2[m]> / (max(||x1||,eps)*max(||x2||,eps))
// Round 15: REVERT to round-13 (best: 166.6 us total, GEMM ~150 us ~= 916 TF).
// r14's 32x32x16 experiment: MfmaUtil 32->37.5 but SQ_LDS_BANK_CONFLICT 0->16.8M
// (32-row fragment reads defeat the XOR swizzle; padding fix unavailable under
// global_load_lds linear-dest constraint) -> net regression. 16x16x32 restored.
//
// Winning structure (verified): 128x128 tile, BK=64, 4 waves (2x2),
// SINGLE-buffered 32 KB LDS, simple 2-sync loop, compiler-scheduled waits;
// engine = INTER-BLOCK overlap (__launch_bounds__(256,4), ~52 VGPR -> 4
// blocks/CU co-resident; one block's staging drain overlaps another's MFMA).
// + 2-D supertile block mapping (L2-fed staging), zero-conflict XOR-swizzled
// LDS (pre-swizzled global source + swizzled read), merged norm pass.
// This is at the documented plain-HIP ceiling for the m97-family structure
// (874-912 TF); 8-phase attempts (r5/r8/r11/r12) capped at 745 TF; fp8/MX
// excluded by the 3.3e-3 absmax budget.

typedef __bf16 bf16x8 __attribute__((ext_vector_type(8)));
typedef float  f32x4  __attribute__((ext_vector_type(4)));

#define LDSP(x) ((__attribute__((address_space(3))) void*)(x))
#define GLBP(x) ((const __attribute__((address_space(1))) void*)(x))

#define BM 128
#define BN 128
#define BK 64
#define EPS_CS 1e-8f

// ------------- normalize: one block per row of x1 or x2, D == 1024 -------------

__global__ __launch_bounds__(256) void nrm_bf16_1024_2(const float* __restrict__ in1,
                                                       const float* __restrict__ in2,
                                                       __bf16* __restrict__ out1,
                                                       __bf16* __restrict__ out2,
                                                       int NR) {
    const int r = blockIdx.x;
    const float* in = (r < NR) ? in1 : in2;
    __bf16* out = (r < NR) ? out1 : out2;
    const int row = (r < NR) ? r : r - NR;
    const int t = threadIdx.x;
    const float4 v = reinterpret_cast<const float4*>(in + (size_t)row * 1024)[t];
    float ss = v.x * v.x + v.y * v.y + v.z * v.z + v.w * v.w;
#pragma unroll
    for (int off = 32; off > 0; off >>= 1) ss += __shfl_down(ss, off, 64);
    __shared__ float red[4];
    const int lane = t & 63, wid = t >> 6;
    if (lane == 0) red[wid] = ss;
    __syncthreads();
    const float tot = red[0] + red[1] + red[2] + red[3];
    const float rn = 1.0f / fmaxf(sqrtf(tot), EPS_CS);
    ushort4 pk;
    pk.x = __builtin_bit_cast(unsigned short, (__bf16)(v.x * rn));
    pk.y = __builtin_bit_cast(unsigned short, (__bf16)(v.y * rn));
    pk.z = __builtin_bit_cast(unsigned short, (__bf16)(v.z * rn));
    pk.w = __builtin_bit_cast(unsigned short, (__bf16)(v.w * rn));
    reinterpret_cast<ushort4*>(out + (size_t)row * 1024)[t] = pk;
}

// ---------------- 128x128 m97-structure MFMA GEMM:  C = A * B^T ----------------
// A[NR][D], B[NC][D] bf16 row-major; C[NR][NC] f32. NR,NC % 128 == 0, D % 64 == 0.
// Grid = (NR/128)*(NC/128), block = 256 (4 waves, 2x2). Per wave: 64x64 output,
// acc[4][4] f32x4 = 64 VGPR. LDS: A[128x64] + B[128x64] bf16 = 32 KB, single-buf.
// __launch_bounds__(256,4): 4 waves/EU -> VGPR<=128 -> 4 blocks/CU co-resident.

__global__ __launch_bounds__(256, 4) void gemm_nt_bf16_128(const __bf16* __restrict__ A,
                                                           const __bf16* __restrict__ B,
                                                           float* __restrict__ C,
                                                           int NC, int D) {
    __shared__ alignas(16) __bf16 As[BM * BK];   // 16 KB
    __shared__ alignas(16) __bf16 Bs[BN * BK];   // 16 KB

    const int t    = threadIdx.x;
    const int lane = t & 63;
    const int wid  = t >> 6;            // 0..3
    const int wr   = wid >> 1;          // wave row 0..1 (64-row strips)
    const int wc   = wid & 1;           // wave col 0..1 (64-col strips)
    const int fr   = lane & 15;         // fragment row/col within 16
    const int fq   = lane >> 4;         // 0..3 (k sub-group)
    const int xk   = fr & 7;            // read XOR key == (row & 7)
    const int g0   = fq ^ xk;           // kh=0 physical 16B-group
    const int g1   = (4 + fq) ^ xk;     // kh=1 physical 16B-group

    // ---- block -> tile mapping: 2-D supertile (16 rows x 8 cols per XCD) ----
    const int nwg = gridDim.x;
    const int ntn = NC / BN;
    const int ntm = nwg / ntn;
    int tr, tc;
    if (ntn == 64 && (ntm & 15) == 0) {
        const int xcd = blockIdx.x & 7;
        const int i   = blockIdx.x >> 3;    // 0 .. nwg/8-1
        const int gen = i >> 7;             // supertile generation (16 tile-rows each)
        const int w   = i & 127;            // position within 16x8 supertile
        tr = gen * 16 + (w & 15);
        tc = xcd * 8 + (w >> 4);
    } else if ((nwg & 7) == 0) {
        const int swz = (blockIdx.x & 7) * (nwg >> 3) + (blockIdx.x >> 3);
        tr = swz / ntn; tc = swz % ntn;
    } else {
        tr = blockIdx.x / ntn; tc = blockIdx.x % ntn;
    }
    const int brow = tr * BM;
    const int bcol = tc * BN;

    // staging: thread t covers LDS elements [s*8, s*8+8) of slab s = i*256+t.
    // row = i*32 + (t>>3), lds k-group = t&7; global k-group pre-swizzled:
    // (t&7) ^ (row&7)  (inverse of the read XOR).
    const int srow = t >> 3;                         // 0..31
    const int sg8  = ((t & 7) ^ (srow & 7)) << 3;
    const __bf16* aSrc = A + (size_t)(brow + srow) * D + sg8;
    const __bf16* bSrc = B + (size_t)(bcol + srow) * D + sg8;

    f32x4 acc[4][4];
#pragma unroll
    for (int m = 0; m < 4; ++m)
#pragma unroll
        for (int n = 0; n < 4; ++n)
            acc[m][n] = (f32x4){0.f, 0.f, 0.f, 0.f};

    const int NT = D / BK;
    for (int kt = 0; kt < NT; ++kt) {
        const int k0 = kt * BK;
        // ---- stage A,B tiles (128x64 bf16 each) via global_load_lds x16B ----
#pragma unroll
        for (int i = 0; i < 4; ++i)
            __builtin_amdgcn_global_load_lds(
                GLBP(aSrc + (size_t)(i * 32) * D + k0),
                LDSP(&As[(i * 256 + t) * 8]), 16, 0, 0);
#pragma unroll
        for (int i = 0; i < 4; ++i)
            __builtin_amdgcn_global_load_lds(
                GLBP(bSrc + (size_t)(i * 32) * D + k0),
                LDSP(&Bs[(i * 256 + t) * 8]), 16, 0, 0);
        __syncthreads();   // compiler drains vmcnt before s_barrier

        // ---- compute: 2 k-slices of 32, 16 MFMA each ----
#pragma unroll
        for (int kk = 0; kk < 2; ++kk) {
            const int g = kk ? g1 : g0;
            bf16x8 af[4], bf[4];
#pragma unroll
            for (int m = 0; m < 4; ++m)
                af[m] = *reinterpret_cast<const bf16x8*>(&As[(wr * 64 + m * 16 + fr) * BK + g * 8]);
#pragma unroll
            for (int n = 0; n < 4; ++n)
                bf[n] = *reinterpret_cast<const bf16x8*>(&Bs[(wc * 64 + n * 16 + fr) * BK + g * 8]);
#pragma unroll
            for (int m = 0; m < 4; ++m)
#pragma unroll
                for (int n = 0; n < 4; ++n)
                    acc[m][n] = __builtin_amdgcn_mfma_f32_16x16x32_bf16(af[m], bf[n], acc[m][n], 0, 0, 0);
        }
        __syncthreads();   // protect LDS from next iteration's staging
    }

    // ---- epilogue: D[row][col], col = lane&15, row = (lane>>4)*4 + reg ----
    const int crow0 = brow + wr * 64;
    const int ccol0 = bcol + wc * 64;
    const int rr    = fq * 4;
#pragma unroll
    for (int m = 0; m < 4; ++m) {
#pragma unroll
        for (int r = 0; r < 4; ++r) {
            const size_t rowoff = (size_t)(crow0 + m * 16 + rr + r) * NC;
#pragma unroll
            for (int n = 0; n < 4; ++n)
                C[rowoff + ccol0 + n * 16 + fr] = acc[m][n][r];
        }
    }
}

// ---------------- fallback path (odd shapes / tiny ws) ----------------

__global__ __launch_bounds__(256) void rnorm_rows(const float* __restrict__ in,
                                                  float* __restrict__ rn, int D) {
    const int row = blockIdx.x;
    float ss = 0.f;
    for (int c = threadIdx.x; c < D; c += 256) {
        const float v = in[(size_t)row * D + c];
        ss += v * v;
    }
#pragma unroll
    for (int off = 32; off > 0; off >>= 1) ss += __shfl_down(ss, off, 64);
    __shared__ float red[4];
    if ((threadIdx.x & 63) == 0) red[threadIdx.x >> 6] = ss;
    __syncthreads();
    if (threadIdx.x == 0) {
        const float tot = red[0] + red[1] + red[2] + red[3];
        rn[row] = 1.0f / fmaxf(sqrtf(tot), EPS_CS);
    }
}

__global__ __launch_bounds__(256) void gemm_f32_fallback(const float* __restrict__ x1,
                                                         const float* __restrict__ x2,
                                                         const float* __restrict__ rn1,
                                                         const float* __restrict__ rn2,
                                                         float* __restrict__ C,
                                                         int NR, int NC, int D) {
    __shared__ float a[16][17], b[16][17];
    const int tx = threadIdx.x & 15, ty = threadIdx.x >> 4;
    const int row = blockIdx.y * 16 + ty;
    const int colb = blockIdx.x * 16;
    float acc = 0.f;
    for (int k0 = 0; k0 < D; k0 += 16) {
        a[ty][tx] = (row < NR && k0 + tx < D) ? x1[(size_t)row * D + k0 + tx] : 0.f;
        b[ty][tx] = (colb + ty < NC && k0 + tx < D) ? x2[(size_t)(colb + ty) * D + k0 + tx] : 0.f;
        __syncthreads();
#pragma unroll
        for (int k = 0; k < 16; ++k) acc += a[ty][k] * b[tx][k];
        __syncthreads();
    }
    if (row < NR && colb + tx < NC)
        C[(size_t)row * NC + colb + tx] = acc * rn1[row] * rn2[colb + tx];
}

// ---------------- launch ----------------

extern "C" void kernel_launch(void* const* d_in, const int* in_sizes, int n_in,
                              void* d_out, int out_size, void* d_ws, size_t ws_size,
                              hipStream_t stream) {
    const float* x1 = (const float*)d_in[0];
    const float* x2 = (const float*)d_in[1];
    float* C = (float*)d_out;

    const int D  = 1024;
    const int NR = in_sizes[0] / D;
    const int NC = in_sizes[1] / D;

    const size_t need = ((size_t)NR + (size_t)NC) * (size_t)D * sizeof(__bf16);
    const bool fast = (in_sizes[0] % D == 0) && (in_sizes[1] % D == 0) &&
                      (NR % BM == 0) && (NC % BN == 0) && (D % BK == 0) &&
                      (ws_size >= need);

    if (fast) {
        __bf16* An = (__bf16*)d_ws;
        __bf16* Bn = An + (size_t)NR * D;
        nrm_bf16_1024_2<<<NR + NC, 256, 0, stream>>>(x1, x2, An, Bn, NR);
        const int grid = (NR / BM) * (NC / BN);
        gemm_nt_bf16_128<<<grid, 256, 0, stream>>>(An, Bn, C, NC, D);
    } else {
        float* rn1 = (float*)d_ws;
        float* rn2 = rn1 + NR;
        rnorm_rows<<<NR, 256, 0, stream>>>(x1, rn1, D);
        rnorm_rows<<<NC, 256, 0, stream>>>(x2, rn2, D);
        dim3 g((NC + 15) / 16, (NR + 15) / 16);
        gemm_f32_fallback<<<g, 256, 0, stream>>>(x1, x2, rn1, rn2, C, NR, NC, D);
    }
}